// Round 1
// baseline (70.399 us; speedup 1.0000x reference)
//
#include <hip/hip_runtime.h>

// Autoregressive bisection inverter, B=512 rows, D=64 dims.
// Key insight: W is STRICTLY lower triangular, so the scalar function the
// reference bisects, g(xi) = softplus(a_i)*xi + sum_{j<i} W[i,j]*tanh(x_j) - y_i,
// is linear in xi with positive slope. The bisection (TOL=1e-6) converges to the
// exact root (y_i - c_i)/softplus(a_i) whenever that root is inside [-10,10].
// We compute the exact root; a faithful emulation of the reference's (buggy)
// adapt-interval + bisection handles the (measure-~zero) out-of-range case.

#define DD 64
#define LOWERB (-10.0f)
#define UPPERB (10.0f)

__device__ __forceinline__ float sgnf(float v) {
    return (v > 0.f) ? 1.f : ((v < 0.f) ? -1.f : 0.f);
}

// Faithful port of _adapt_interval (incl. lagged-sign evaluation) + _bisection
// for the linear function f(x) = s*x + cmy  (cmy = c - y), s > 0.
__device__ __attribute__((noinline)) float bisect_fallback(float s, float cmy) {
    float lo = LOWERB, up = UPPERB, e = UPPERB - LOWERB;
    float sl = sgnf(fmaf(s, lo, cmy));
    float su = sgnf(fmaf(s, up, cmy));
    int it = 0;
    while (sl == su && it < 200) {
        float nlo = (sl == 1.f) ? (lo - e) : up;
        float nup = (sl == 1.f) ? lo : (up + e);
        // reference evaluates signs at the PRE-update bounds (the "bug")
        float osl = sgnf(fmaf(s, lo, cmy));
        float osu = sgnf(fmaf(s, up, cmy));
        lo = nlo; up = nup; e *= 2.f; sl = osl; su = osu; ++it;
    }
    it = 0;
    while ((up - lo) > 2e-6f && it < 200) {
        float mid = 0.5f * (lo + up);
        bool pos = fmaf(s, mid, cmy) >= 0.f;
        if (pos) up = mid; else lo = mid;
        ++it;
    }
    return 0.5f * (lo + up);
}

__device__ __forceinline__ float rl(float v, int l) {
    return __int_as_float(__builtin_amdgcn_readlane(__float_as_int(v), l));
}

__global__ __launch_bounds__(256) void ar_invert_kernel(
    const float* __restrict__ y, const float* __restrict__ a,
    const float* __restrict__ W, float* __restrict__ out, int B)
{
    // Stage W transposed into LDS: Wt[j][i] = W[i][j], leading dim 65 to keep
    // both the staging writes and the per-step reads bank-conflict-free.
    __shared__ float Wt[DD * (DD + 1)];
    for (int k = threadIdx.x; k < DD * DD; k += 256) {
        int i = k >> 6, j = k & 63;          // consecutive threads -> consecutive j: coalesced global read
        Wt[j * (DD + 1) + i] = W[k];
    }
    __syncthreads();

    const int lane = threadIdx.x & 63;
    const int row  = (int)((blockIdx.x * 256u + threadIdx.x) >> 6);  // one wave per row
    if (row >= B) return;

    float yv = y[row * DD + lane];
    float av = a[lane];
    // jax.nn.softplus(a) = logaddexp(a, 0) = a + log1p(exp(-a)) for a > 0
    float s  = av + log1pf(expf(-av));
    float rs = 1.f / s;

    float c = 0.f;   // running c_i = sum_{j<i} W[i,j] * tanh(x_j), held by lane i
    float x = 0.f;

    for (int j = 0; j < DD; ++j) {
        // broadcast lane j's state (j is wave-uniform -> v_readlane, cheap)
        float cj  = rl(c, j);
        float yj  = rl(yv, j);
        float rsj = rl(rs, j);
        float r = (yj - cj) * rsj;           // exact root of s*x + (c - y)

        // faithful-path guard: if the root is not bracketed by [-10,10] the
        // reference's buggy adapt-interval gives a different answer — emulate it.
        float sj  = rl(s, j);
        float cmy = cj - yj;
        float flo = fmaf(sj, LOWERB, cmy);
        float fup = fmaf(sj, UPPERB, cmy);
        if (sgnf(flo) == sgnf(fup)) {
            r = bisect_fallback(sj, cmy);
        }

        float t = tanhf(r);                  // all lanes redundantly: no divergence
        if (lane == j) x = r;
        c = fmaf(Wt[j * (DD + 1) + lane], t, c);  // W[lane][j] == 0 for lane <= j
    }

    out[row * DD + lane] = x;
}

extern "C" void kernel_launch(void* const* d_in, const int* in_sizes, int n_in,
                              void* d_out, int out_size, void* d_ws, size_t ws_size,
                              hipStream_t stream) {
    const float* y = (const float*)d_in[0];
    const float* a = (const float*)d_in[1];
    const float* W = (const float*)d_in[2];
    float* out = (float*)d_out;
    const int B = in_sizes[0] / DD;          // 512
    const int threads = 256;                 // 4 rows (waves) per block
    const int blocks = (B * DD + threads - 1) / threads;
    ar_invert_kernel<<<blocks, threads, 0, stream>>>(y, a, W, out, B);
}

// Round 2
// 67.265 us; speedup vs baseline: 1.0466x; 1.0466x over previous
//
#include <hip/hip_runtime.h>

// Autoregressive bisection inverter, B=512 rows, D=64 dims.
// W is STRICTLY lower triangular, so the bisected scalar function
// g(xi) = softplus(a_i)*xi + sum_{j<i} W[i,j]*tanh(x_j) - y_i
// is linear in xi with positive slope; bisection (TOL=1e-6) converges to the
// exact root (y_i - c_i)/softplus(a_i) whenever it lies in [-10,10].
// Hot path: one wave per row, lane i carries u_i = y_i - c_i; step j
// broadcasts u_j via v_readlane, all lanes compute tanh redundantly
// (wave-uniform, no divergence), one FMA updates u. W row in VGPRs, no LDS,
// no calls, fully unrolled. The (practically never-taken) out-of-range case
// sets a uniform flag and is replayed faithfully in a cold block.

#define DD 64
#define LOWERB (-10.0f)
#define UPPERB (10.0f)
#define K2 2.8853900817779268f   // 2*log2(e)

__device__ __forceinline__ float sgnf(float v) {
    return (v > 0.f) ? 1.f : ((v < 0.f) ? -1.f : 0.f);
}

__device__ __forceinline__ float rl(float v, int l) {
    return __int_as_float(__builtin_amdgcn_readlane(__float_as_int(v), l));
}

// t = 1 - 2/(exp(2r)+1); exp2(+inf)->inf->rcp 0->t=1; exp2(-inf)->0->t=-1.
__device__ __forceinline__ float tanh_fast_arg(float r_times_k2) {
    float e = __builtin_amdgcn_exp2f(r_times_k2);
    return fmaf(-2.f, __builtin_amdgcn_rcpf(e + 1.f), 1.f);
}

// Faithful port of _adapt_interval (incl. lagged-sign evaluation at the
// PRE-update bounds) + _bisection for the linear f(x) = s*x + cmy, s > 0.
__device__ __attribute__((noinline)) float bisect_fallback(float s, float cmy) {
    float lo = LOWERB, up = UPPERB, e = UPPERB - LOWERB;
    float sl = sgnf(fmaf(s, lo, cmy));
    float su = sgnf(fmaf(s, up, cmy));
    int it = 0;
    while (sl == su && it < 200) {
        float nlo = (sl == 1.f) ? (lo - e) : up;
        float nup = (sl == 1.f) ? lo : (up + e);
        float osl = sgnf(fmaf(s, lo, cmy));   // lagged signs (the reference bug)
        float osu = sgnf(fmaf(s, up, cmy));
        lo = nlo; up = nup; e *= 2.f; sl = osl; su = osu; ++it;
    }
    it = 0;
    while ((up - lo) > 2e-6f && it < 200) {
        float mid = 0.5f * (lo + up);
        bool pos = fmaf(s, mid, cmy) >= 0.f;
        if (pos) up = mid; else lo = mid;
        ++it;
    }
    return 0.5f * (lo + up);
}

__global__ __launch_bounds__(256) void ar_invert_kernel(
    const float* __restrict__ y, const float* __restrict__ a,
    const float* __restrict__ W, float* __restrict__ out, int B)
{
    const int lane = threadIdx.x & 63;
    const int row  = (int)((blockIdx.x * 256u + threadIdx.x) >> 6);
    if (row >= B) return;

    // W row of this lane into registers (off the critical chain entirely).
    float wr[DD];
    const float4* w4 = (const float4*)(W + lane * DD);
    #pragma unroll
    for (int k = 0; k < DD / 4; ++k) {
        float4 v = w4[k];
        wr[4 * k + 0] = v.x; wr[4 * k + 1] = v.y;
        wr[4 * k + 2] = v.z; wr[4 * k + 3] = v.w;
    }

    const float u0 = y[row * DD + lane];
    float u = u0;                         // u_i = y_i - c_i
    float av = a[lane];
    float s  = av + log1pf(expf(-av));    // softplus, a > 0
    float rs  = 1.f / s;
    float rs2 = rs * K2;

    float x = 0.f;
    bool bad = false;                     // wave-uniform (operands are broadcasts)

    #pragma unroll
    for (int j = 0; j < DD; ++j) {
        float uj  = rl(u, j);
        float sj  = rl(s, j);
        // reference triggers adapt_interval when sign(f(-10)) == sign(f(10));
        // f(b) = s*b + (c - y) = s*b - u
        float flo = fmaf(sj, LOWERB, -uj);
        float fup = fmaf(sj, UPPERB, -uj);
        bad = bad || (sgnf(flo) == sgnf(fup));
        float r = uj * rl(rs, j);                 // exact root (off-chain, output only)
        float t = tanh_fast_arg(uj * rl(rs2, j)); // chain: readlane->mul->exp->add->rcp->fma
        if (lane == j) x = r;
        u = fmaf(-wr[j], t, u);                   // W[lane][j]==0 for lane<=j
    }

    if (bad) {
        // Cold faithful replay from scratch with the reference's buggy
        // adapt-interval + bisection for any out-of-range coordinate.
        u = u0; x = 0.f;
        for (int j = 0; j < DD; ++j) {
            float uj = rl(u, j);
            float sj = rl(s, j);
            float flo = fmaf(sj, LOWERB, -uj);
            float fup = fmaf(sj, UPPERB, -uj);
            float r;
            if (sgnf(flo) == sgnf(fup)) r = bisect_fallback(sj, -uj);
            else                        r = uj * rl(rs, j);
            float t = tanhf(r);
            if (lane == j) x = r;
            u = fmaf(-wr[j], t, u);
        }
    }

    out[row * DD + lane] = x;
}

extern "C" void kernel_launch(void* const* d_in, const int* in_sizes, int n_in,
                              void* d_out, int out_size, void* d_ws, size_t ws_size,
                              hipStream_t stream) {
    const float* y = (const float*)d_in[0];
    const float* a = (const float*)d_in[1];
    const float* W = (const float*)d_in[2];
    float* out = (float*)d_out;
    const int B = in_sizes[0] / DD;          // 512
    const int threads = 256;                 // 4 rows (waves) per block
    const int blocks = (B * DD + threads - 1) / threads;
    ar_invert_kernel<<<blocks, threads, 0, stream>>>(y, a, W, out, B);
}